// Round 1
// baseline (153.722 us; speedup 1.0000x reference)
//
#include <hip/hip_runtime.h>

// TanhAttention: B=4, L=512, D=256
//   pair = tanh(H[b,i,:] + H[b,j,:])            (B,L,L,D)
//   scores = pair @ w + bias                    (B,L,L)
//   alpha = softmax(scores, axis=-1)
//   r = alpha @ H                               (B,L,D)
// Outputs concatenated: r (524288 floats) then alpha (1048576 floats).
//
// Trick 1: score = (Sum_d w_d + bias) - 2*Sum_d w_d * r_d,  r_d = 1/(1+exp2(K*(hi+hj)))
//          with K = 2*log2(e) pre-multiplied into the LDS copy of H.
// Trick 2: softmax is shift-invariant -> the row-constant (Sum w + bias) cancels;
//          alpha = softmax_j(-2*acc). Bias never needed.
// Inner loop per element: v_add, v_exp_f32, v_add, v_rcp_f32, v_fmac -> trans-pipe bound.

#define B_ 4
#define L_ 512
#define D_ 256
#define TI 8            // i-rows per block
#define DT 16           // d-tile staged in LDS
#define PSTR 17         // padded LDS row stride (odd -> conflict-free)
#define NTHREADS 512

__global__ __launch_bounds__(NTHREADS, 1) void tanh_attn_kernel(
    const float* __restrict__ H, const float* __restrict__ w,
    float* __restrict__ rOut, float* __restrict__ aOut)
{
    __shared__ float hjs[L_ * PSTR];   // 512*17*4 = 34816 B  (K-scaled H[b] d-tile)
    __shared__ float sc[TI * L_];      // 16384 B  (scores, then alpha)
    __shared__ float ws[D_];           // 1024 B

    const int tid = threadIdx.x;
    const int blk = blockIdx.x;        // 0..255
    const int b   = blk >> 6;          // /(L_/TI)
    const int i0  = (blk & 63) * TI;

    const float K = 2.8853900817779268f;  // 2*log2(e)

    if (tid < D_) ws[tid] = w[tid];

    const int ti = tid >> 7;           // 0..3   (i micro: i = i0 + ti + 4*ii)
    const int tj = tid & 127;          // 0..127 (j micro: j = tj + 128*jj -> lane-stride-1 LDS)

    float acc[2][4];
    #pragma unroll
    for (int ii = 0; ii < 2; ++ii)
        #pragma unroll
        for (int jj = 0; jj < 4; ++jj) acc[ii][jj] = 0.0f;

    const float* Hb = H + (size_t)b * L_ * D_;

    for (int dt = 0; dt < D_ / DT; ++dt) {
        const int d0 = dt * DT;
        __syncthreads();   // previous tile's readers done (also covers ws on dt=0)
        // Stage 512 rows x DT cols, scaled by K. 2048 float4 / 512 threads = 4 each.
        #pragma unroll
        for (int rr = 0; rr < 4; ++rr) {
            int idx = rr * NTHREADS + tid;   // 0..2047
            int j   = idx >> 2;              // 4 float4 per row-tile
            int q   = idx & 3;
            const float4 hv = *(const float4*)(Hb + j * D_ + d0 + q * 4);
            float* dst = &hjs[j * PSTR + q * 4];
            dst[0] = hv.x * K; dst[1] = hv.y * K; dst[2] = hv.z * K; dst[3] = hv.w * K;
        }
        __syncthreads();

        #pragma unroll 4
        for (int dd = 0; dd < DT; ++dd) {
            const float wv  = ws[d0 + dd];
            float hi[2], hj[4];
            hi[0] = hjs[(i0 + ti    ) * PSTR + dd];   // wave-uniform broadcast
            hi[1] = hjs[(i0 + ti + 4) * PSTR + dd];
            hj[0] = hjs[(tj        ) * PSTR + dd];    // lane stride 17 -> no conflicts
            hj[1] = hjs[(tj + 128  ) * PSTR + dd];
            hj[2] = hjs[(tj + 256  ) * PSTR + dd];
            hj[3] = hjs[(tj + 384  ) * PSTR + dd];
            #pragma unroll
            for (int ii = 0; ii < 2; ++ii) {
                #pragma unroll
                for (int jj = 0; jj < 4; ++jj) {
                    float a = hi[ii] + hj[jj];                       // = K*(Hi+Hj)
                    float e = __builtin_amdgcn_exp2f(a);             // e^{2(Hi+Hj)}
                    float r = __builtin_amdgcn_rcpf(e + 1.0f);       // sigmoid(-2x)
                    acc[ii][jj] = fmaf(wv, r, acc[ii][jj]);
                }
            }
        }
    }

    // ---- scores (shifted) to LDS ----
    __syncthreads();
    #pragma unroll
    for (int ii = 0; ii < 2; ++ii)
        #pragma unroll
        for (int jj = 0; jj < 4; ++jj)
            sc[(ti + 4 * ii) * L_ + tj + 128 * jj] = -2.0f * acc[ii][jj];
    __syncthreads();

    // ---- softmax: one wave per row ----
    const int row  = tid >> 6;    // 0..7
    const int lane = tid & 63;
    {
        float v[8];
        float m = -1e30f;
        #pragma unroll
        for (int k = 0; k < 8; ++k) {
            v[k] = sc[row * L_ + lane + 64 * k];
            m = fmaxf(m, v[k]);
        }
        #pragma unroll
        for (int off = 1; off < 64; off <<= 1)
            m = fmaxf(m, __shfl_xor(m, off, 64));
        const float L2E = 1.4426950408889634f;
        float s = 0.0f;
        #pragma unroll
        for (int k = 0; k < 8; ++k) {
            v[k] = __builtin_amdgcn_exp2f((v[k] - m) * L2E);
            s += v[k];
        }
        #pragma unroll
        for (int off = 1; off < 64; off <<= 1)
            s += __shfl_xor(s, off, 64);
        const float inv = __builtin_amdgcn_rcpf(s);
        float* aRow = aOut + ((size_t)(b * L_ + i0 + row)) * L_;
        #pragma unroll
        for (int k = 0; k < 8; ++k) {
            float a = v[k] * inv;
            sc[row * L_ + lane + 64 * k] = a;   // keep alpha in LDS for r-phase
            aRow[lane + 64 * k] = a;
        }
    }
    __syncthreads();

    // ---- r[i,:] = sum_j alpha[i,j] * H[b,j,:]  (float4 over d) ----
    {
        const int i  = row;          // 0..7
        const int d4 = lane;         // 0..63 float4 index
        const float4* Hb4 = (const float4*)Hb;   // [512][64]
        float4 racc = {0.0f, 0.0f, 0.0f, 0.0f};
        #pragma unroll 8
        for (int j = 0; j < L_; ++j) {
            float a  = sc[i * L_ + j];           // wave-uniform broadcast
            float4 h = Hb4[(size_t)j * (D_ / 4) + d4];
            racc.x = fmaf(a, h.x, racc.x);
            racc.y = fmaf(a, h.y, racc.y);
            racc.z = fmaf(a, h.z, racc.z);
            racc.w = fmaf(a, h.w, racc.w);
        }
        float4* R4 = (float4*)rOut;
        R4[((size_t)(b * L_ + i0 + i)) * (D_ / 4) + d4] = racc;
    }
}

extern "C" void kernel_launch(void* const* d_in, const int* in_sizes, int n_in,
                              void* d_out, int out_size, void* d_ws, size_t ws_size,
                              hipStream_t stream) {
    const float* H = (const float*)d_in[0];
    const float* w = (const float*)d_in[1];
    // d_in[2] (bias) unused: softmax shift-invariance cancels it.
    float* rOut = (float*)d_out;
    float* aOut = rOut + (size_t)B_ * L_ * D_;
    dim3 grid(B_ * (L_ / TI));   // 256 blocks
    tanh_attn_kernel<<<grid, NTHREADS, 0, stream>>>(H, w, rOut, aOut);
}